// Round 1
// 347.384 us; speedup vs baseline: 1.5650x; 1.5650x over previous
//
#include <hip/hip_runtime.h>

typedef __attribute__((ext_vector_type(8))) _Float16 half8;
typedef __attribute__((ext_vector_type(4))) _Float16 half4;
typedef __attribute__((ext_vector_type(4))) float f32x4;

__device__ __forceinline__ _Float16 f2h(float f) { return (_Float16)f; }

#define LOG100 4.605170185988091f
#define NEGBIG -30000.0f

// ---------------- K0a: mask bits in TRANSPOSED MFMA-fragment layout ----------------
// For S^T tiles: C pos (row=token=quad*4+rr, col=qrow=ln15).
// mb[w][qt][kt][lane] u8, bit rr = allowed(R = qt*16+ln15, col = kt*16+quad*4+rr)
__global__ void k_maskb(const float* __restrict__ mask, unsigned char* __restrict__ mb) {
  int tid = blockIdx.x * 256 + threadIdx.x;
  if (tid >= 64 * 484 * 64) return;
  int lane = tid & 63, idx = tid >> 6;
  int kt = idx % 22, t2 = idx / 22;
  int qt = t2 % 22, w = t2 / 22;
  int R = qt * 16 + (lane & 15), col0 = kt * 16 + (lane >> 4) * 4;
  unsigned bits = 0;
#pragma unroll
  for (int rr = 0; rr < 4; rr++) {
    int col = col0 + rr;
    bool pass = true;
    if (R < 343 && col < 343) pass = mask[((size_t)w * 343 + R) * 343 + col] > -50.f;
    bits |= (pass ? 1u : 0u) << rr;
  }
  mb[tid] = (unsigned char)bits;
}

// ---------------- K0b: rel-pos bias in TRANSPOSED MFMA-fragment layout ----
// bf[h][qt][kt][lane][rr] = bias(R = qt*16+ln15, col = kt*16+quad*4+rr); pads -> -30000
__global__ void k_biasf(const int* __restrict__ rpi, const float* __restrict__ table,
                        _Float16* __restrict__ bf) {
  int tid = blockIdx.x * 256 + threadIdx.x;
  if (tid >= 3 * 484 * 64) return;
  int lane = tid & 63, idx = tid >> 6;
  int kt = idx % 22, t2 = idx / 22;
  int qt = t2 % 22, h = t2 / 22;
  int R = qt * 16 + (lane & 15), col0 = kt * 16 + (lane >> 4) * 4;
  half4 o;
#pragma unroll
  for (int rr = 0; rr < 4; rr++) {
    int col = col0 + rr;
    float b = (R < 343 && col < 343) ? table[rpi[R * 343 + col] * 3 + h] : NEGBIG;
    o[rr] = f2h(b);
  }
  reinterpret_cast<half4*>(bf)[tid] = o;
}

// ---------------- K1: qkv = x @ Wqkv^T + b; normalize q,k; fold scale into q ----
__global__ __launch_bounds__(1024, 1) void k_qkv(
    const float* __restrict__ x, const float* __restrict__ Wqkv,
    const float* __restrict__ bqkv, const float* __restrict__ ls,
    _Float16* __restrict__ q_ws, _Float16* __restrict__ k_ws, _Float16* __restrict__ v_ws) {
  __shared__ alignas(16) _Float16 Wl[288 * 104];
  const int tid = threadIdx.x;
  for (int i = tid; i < 6912; i += 1024) {
    f32x4 w4 = reinterpret_cast<const f32x4*>(Wqkv)[i];
    int f = i * 4, row = f / 96, col = f - row * 96;
    _Float16* dst = &Wl[row * 104 + col];
    dst[0] = f2h(w4[0]); dst[1] = f2h(w4[1]); dst[2] = f2h(w4[2]); dst[3] = f2h(w4[3]);
  }
  __syncthreads();
  const int lane = tid & 63, wv = tid >> 6;
  const int ln15 = lane & 15, quad = lane >> 4;
  const int rowbase = blockIdx.x * 256 + wv * 16;
  const int arow = rowbase + ln15;

  half8 afr[3];
#pragma unroll
  for (int kt = 0; kt < 3; kt++) {
    const float* xp = x + (size_t)arow * 96 + kt * 32 + quad * 8;
    f32x4 a0 = *reinterpret_cast<const f32x4*>(xp);
    f32x4 a1 = *reinterpret_cast<const f32x4*>(xp + 4);
    half8 a;
    a[0] = f2h(a0[0]); a[1] = f2h(a0[1]); a[2] = f2h(a0[2]); a[3] = f2h(a0[3]);
    a[4] = f2h(a1[0]); a[5] = f2h(a1[1]); a[6] = f2h(a1[2]); a[7] = f2h(a1[3]);
    afr[kt] = a;
  }

  int Bb[4], Nn[4];
#pragma unroll
  for (int rr = 0; rr < 4; rr++) {
    int R = rowbase + quad * 4 + rr;
    Bb[rr] = R / 343;
    Nn[rr] = R - Bb[rr] * 343;
  }

  auto ctile = [&](int nt) -> f32x4 {
    f32x4 c = {0.f, 0.f, 0.f, 0.f};
#pragma unroll
    for (int kt = 0; kt < 3; kt++) {
      half8 b = *reinterpret_cast<const half8*>(&Wl[(nt * 16 + ln15) * 104 + kt * 32 + quad * 8]);
      c = __builtin_amdgcn_mfma_f32_16x16x32_f16(afr[kt], b, c, 0, 0, 0);
    }
    return c;
  };

#pragma unroll
  for (int h = 0; h < 3; h++) {
    float sc = __expf(fminf(ls[h], LOG100));
    {
      f32x4 c0 = ctile(2 * h), c1 = ctile(2 * h + 1);
      float b0 = bqkv[32 * h + ln15], b1 = bqkv[32 * h + 16 + ln15];
#pragma unroll
      for (int rr = 0; rr < 4; rr++) { c0[rr] += b0; c1[rr] += b1; }
#pragma unroll
      for (int rr = 0; rr < 4; rr++) {
        float s2 = c0[rr] * c0[rr] + c1[rr] * c1[rr];
        s2 += __shfl_xor(s2, 1); s2 += __shfl_xor(s2, 2);
        s2 += __shfl_xor(s2, 4); s2 += __shfl_xor(s2, 8);
        float inv = sc / fmaxf(sqrtf(s2), 1e-12f);
        size_t base = ((size_t)(Bb[rr] * 3 + h) * 343 + Nn[rr]) * 32;
        q_ws[base + ln15] = f2h(c0[rr] * inv);
        q_ws[base + 16 + ln15] = f2h(c1[rr] * inv);
      }
    }
    {
      f32x4 c0 = ctile(6 + 2 * h), c1 = ctile(7 + 2 * h);
      float b0 = bqkv[96 + 32 * h + ln15], b1 = bqkv[96 + 32 * h + 16 + ln15];
#pragma unroll
      for (int rr = 0; rr < 4; rr++) { c0[rr] += b0; c1[rr] += b1; }
#pragma unroll
      for (int rr = 0; rr < 4; rr++) {
        float s2 = c0[rr] * c0[rr] + c1[rr] * c1[rr];
        s2 += __shfl_xor(s2, 1); s2 += __shfl_xor(s2, 2);
        s2 += __shfl_xor(s2, 4); s2 += __shfl_xor(s2, 8);
        float inv = 1.0f / fmaxf(sqrtf(s2), 1e-12f);
        size_t base = ((size_t)(Bb[rr] * 3 + h) * 343 + Nn[rr]) * 32;
        k_ws[base + ln15] = f2h(c0[rr] * inv);
        k_ws[base + 16 + ln15] = f2h(c1[rr] * inv);
      }
    }
    {
      f32x4 c0 = ctile(12 + 2 * h), c1 = ctile(13 + 2 * h);
      float b0 = bqkv[192 + 32 * h + ln15], b1 = bqkv[192 + 32 * h + 16 + ln15];
#pragma unroll
      for (int rr = 0; rr < 4; rr++) {
        size_t base = ((size_t)(Bb[rr] * 3 + h) * 343 + Nn[rr]) * 32;
        v_ws[base + ln15] = f2h(c0[rr] + b0);
        v_ws[base + 16 + ln15] = f2h(c1[rr] + b1);
      }
    }
  }
}

// ---------------- K2: attention per (b,h). 384 threads (6 waves). ----------------
// One-pass fused softmax (no max shift: cosine attn bounds s <= ~10.1, exp(s) < fp16 max).
// S computed TRANSPOSED via operand swap => P fragment lands token-contiguous per lane:
//   2x ds_write_b64 + 1x ds_read_b128 per 32-token chunk, l-reduce = 2 shuffles.
// No runtime-indexed register arrays anywhere (rule #20) => no scratch.
#define KSTR 40
#define VSTR 352
#define PSTR 40
__global__ __launch_bounds__(384, 3) void k_attn(
    const _Float16* __restrict__ q_ws, const _Float16* __restrict__ k_ws,
    const _Float16* __restrict__ v_ws, const half4* __restrict__ bfrag,
    const unsigned char* __restrict__ mb, _Float16* __restrict__ a_ws) {
  __shared__ alignas(16) _Float16 Kl[344 * KSTR];   // 27520 B
  __shared__ alignas(16) _Float16 Vt[32 * VSTR];    // 22528 B
  __shared__ alignas(16) _Float16 Pl[6][16 * PSTR]; // 7680 B
  const int blk = blockIdx.x;
  const int b = blk / 3, h = blk - b * 3, w = b & 63;
  const size_t slice = (size_t)(b * 3 + h) * 343 * 32;
  const _Float16* qb = q_ws + slice;
  const _Float16* kb = k_ws + slice;
  const _Float16* vb = v_ws + slice;
  const int tid = threadIdx.x, lane = tid & 63, wv = tid >> 6;
  const int ln15 = lane & 15, quad = lane >> 4;

  // stage K rows (row 343 = zeros, clamp target for kt=21 pad lanes)
  for (int i = tid; i < 344 * 4; i += 384) {
    int t = i >> 2, c4 = i & 3;
    half8 kv;
    if (t < 343) kv = *reinterpret_cast<const half8*>(kb + t * 32 + c4 * 8);
    else kv = (half8)(_Float16)0.f;
    *reinterpret_cast<half8*>(&Kl[t * KSTR + c4 * 8]) = kv;
  }
  // stage V transposed
  for (int i = tid; i < 1372; i += 384) {
    int n = i >> 2, c4 = i & 3;
    half8 vv = *reinterpret_cast<const half8*>(vb + n * 32 + c4 * 8);
#pragma unroll
    for (int j = 0; j < 8; j++) Vt[(c4 * 8 + j) * VSTR + n] = vv[j];
  }
  for (int i = tid; i < 288; i += 384) {  // zero token-pad cols 343..351
    int d = i / 9, cc = i - d * 9;
    Vt[d * VSTR + 343 + cc] = (_Float16)0.f;
  }
  __syncthreads();

  _Float16* Pw = Pl[wv];
  const half4* bfh = bfrag + (size_t)h * 484 * 64;
  const unsigned char* mbw = mb + (size_t)w * 484 * 64;

#pragma unroll 1
  for (int qt = wv; qt < 22; qt += 6) {
    const int qbase = qt * 16;
    // Q fragment (used as MFMA B operand): col = ln15 = q-row
    half8 aq = *reinterpret_cast<const half8*>(qb + (size_t)(qbase + ln15) * 32 + quad * 8);
    const half4* bq = bfh + (size_t)qt * 22 * 64 + lane;          // step 64 per kt
    const unsigned char* mq = mbw + (size_t)qt * 22 * 64 + lane;  // step 64 per kt

    f32x4 o0 = {0.f, 0.f, 0.f, 0.f}, o1 = {0.f, 0.f, 0.f, 0.f};  // O^T tiles (dims 0-15 / 16-31)
    float l = 0.f;  // per-lane partial row-sum for qrow = ln15

    half4 b4a = bq[0], b4b = bq[64];
    unsigned mva = mq[0], mvb = mq[64];

#pragma unroll 1
    for (int kc = 0; kc < 11; kc++) {
      // S^T tiles for kt = 2kc, 2kc+1 : mfma(K_frag as A, Q_frag as B)
      int r0 = kc * 32 + ln15;                 // kt=2kc token row (max 335, no clamp needed)
      int r1 = r0 + 16;
      r1 = (r1 > 343) ? 343 : r1;              // kt=21 pad lanes -> zero row
      half8 ak0 = *reinterpret_cast<const half8*>(&Kl[r0 * KSTR + quad * 8]);
      half8 ak1 = *reinterpret_cast<const half8*>(&Kl[r1 * KSTR + quad * 8]);
      f32x4 z = {0.f, 0.f, 0.f, 0.f};
      f32x4 s0 = __builtin_amdgcn_mfma_f32_16x16x32_f16(ak0, aq, z, 0, 0, 0);
      f32x4 s1 = __builtin_amdgcn_mfma_f32_16x16x32_f16(ak1, aq, z, 0, 0, 0);

      // prefetch next chunk's bias/mask fragments (stay in flight across the lgkmcnt fence)
      half4 nb4a = b4a, nb4b = b4b;
      unsigned nmva = mva, nmvb = mvb;
      if (kc < 10) {
        nb4a = bq[(2 * kc + 2) * 64]; nb4b = bq[(2 * kc + 3) * 64];
        nmva = mq[(2 * kc + 2) * 64]; nmvb = mq[(2 * kc + 3) * 64];
      }

      // bias + mask + exp (no shift), accumulate per-lane partial sum
      float p0[4], p1[4];
#pragma unroll
      for (int rr = 0; rr < 4; rr++) {
        float sv0 = s0[rr] + (float)b4a[rr] + (((mva >> rr) & 1u) ? 0.f : -100.f);
        float sv1 = s1[rr] + (float)b4b[rr] + (((mvb >> rr) & 1u) ? 0.f : -100.f);
        p0[rr] = __expf(sv0);
        p1[rr] = __expf(sv1);
        l += p0[rr] + p1[rr];
      }
      // pack P^T: row = qrow = ln15, tokens j*16 + quad*4 + rr (contiguous in rr)
      half4 ph0, ph1;
#pragma unroll
      for (int rr = 0; rr < 4; rr++) { ph0[rr] = f2h(p0[rr]); ph1[rr] = f2h(p1[rr]); }
      *reinterpret_cast<half4*>(&Pw[ln15 * PSTR + quad * 4]) = ph0;
      *reinterpret_cast<half4*>(&Pw[ln15 * PSTR + 16 + quad * 4]) = ph1;

      // RAW fence: LDS ops of a wave complete in order; drain lgkm only (keeps vm prefetch live)
      asm volatile("s_waitcnt lgkmcnt(0)" ::: "memory");

      half8 pb = *reinterpret_cast<const half8*>(&Pw[ln15 * PSTR + quad * 8]);
      half8 v0 = *reinterpret_cast<const half8*>(&Vt[ln15 * VSTR + kc * 32 + quad * 8]);
      half8 v1 = *reinterpret_cast<const half8*>(&Vt[(16 + ln15) * VSTR + kc * 32 + quad * 8]);
      // O^T += V^T(chunk) . P^T(chunk)
      o0 = __builtin_amdgcn_mfma_f32_16x16x32_f16(v0, pb, o0, 0, 0, 0);
      o1 = __builtin_amdgcn_mfma_f32_16x16x32_f16(v1, pb, o1, 0, 0, 0);

      // WAR: next iteration's ds_writes must not be compiler-hoisted above the pb read
      asm volatile("" ::: "memory");

      b4a = nb4a; b4b = nb4b; mva = nmva; mvb = nmvb;
    }

    // full row sum for qrow = ln15: reduce across the 4 quads
    l += __shfl_xor(l, 16);
    l += __shfl_xor(l, 32);

    const int R = qbase + ln15;
    if (R < 343) {
      float inv = 1.0f / l;
      size_t obase = ((size_t)b * 343 + R) * 96 + h * 32;
      half4 w0, w1;
#pragma unroll
      for (int rr = 0; rr < 4; rr++) {
        w0[rr] = f2h(o0[rr] * inv);
        w1[rr] = f2h(o1[rr] * inv);
      }
      *reinterpret_cast<half4*>(a_ws + obase + quad * 4) = w0;       // dims quad*4..+3
      *reinterpret_cast<half4*>(a_ws + obase + 16 + quad * 4) = w1;  // dims 16+quad*4..+3
    }
  }
}

// ---------------- K3: out = attn @ Wproj^T + bproj (fp32 out) ----------------
__global__ __launch_bounds__(1024, 1) void k_proj(
    const _Float16* __restrict__ a_ws, const float* __restrict__ Wproj,
    const float* __restrict__ bproj, float* __restrict__ out) {
  __shared__ alignas(16) _Float16 Wl[96 * 104];
  const int tid = threadIdx.x;
  for (int i = tid; i < 2304; i += 1024) {
    f32x4 w4 = reinterpret_cast<const f32x4*>(Wproj)[i];
    int f = i * 4, row = f / 96, col = f - row * 96;
    _Float16* dst = &Wl[row * 104 + col];
    dst[0] = f2h(w4[0]); dst[1] = f2h(w4[1]); dst[2] = f2h(w4[2]); dst[3] = f2h(w4[3]);
  }
  __syncthreads();
  const int lane = tid & 63, wv = tid >> 6;
  const int ln15 = lane & 15, quad = lane >> 4;
  const int rowbase = blockIdx.x * 256 + wv * 16;
  half8 afr[3];
#pragma unroll
  for (int kt = 0; kt < 3; kt++) {
    afr[kt] = *reinterpret_cast<const half8*>(a_ws + (size_t)(rowbase + ln15) * 96 + kt * 32 + quad * 8);
  }
#pragma unroll
  for (int nt = 0; nt < 6; nt++) {
    f32x4 c = {0.f, 0.f, 0.f, 0.f};
#pragma unroll
    for (int kt = 0; kt < 3; kt++) {
      half8 bfr = *reinterpret_cast<const half8*>(&Wl[(nt * 16 + ln15) * 104 + kt * 32 + quad * 8]);
      c = __builtin_amdgcn_mfma_f32_16x16x32_f16(afr[kt], bfr, c, 0, 0, 0);
    }
    float bb = bproj[nt * 16 + ln15];
#pragma unroll
    for (int rr = 0; rr < 4; rr++) {
      int R = rowbase + quad * 4 + rr;
      out[(size_t)R * 96 + nt * 16 + ln15] = c[rr] + bb;
    }
  }
}

// ---------------- launch ----------------
extern "C" void kernel_launch(void* const* d_in, const int* in_sizes, int n_in,
                              void* d_out, int out_size, void* d_ws, size_t ws_size,
                              hipStream_t stream) {
  const float* x     = (const float*)d_in[0];
  const float* mask  = (const float*)d_in[1];
  const float* Wqkv  = (const float*)d_in[2];
  const float* bqkv  = (const float*)d_in[3];
  const float* Wproj = (const float*)d_in[4];
  const float* bproj = (const float*)d_in[5];
  const float* ls    = (const float*)d_in[6];
  const float* btab  = (const float*)d_in[7];
  const int*   rpi   = (const int*)d_in[8];
  float* out = (float*)d_out;

  char* ws = (char*)d_ws;
  _Float16* q_ws = (_Float16*)(ws);
  _Float16* k_ws = (_Float16*)(ws + 33718272);
  _Float16* v_ws = (_Float16*)(ws + 67436544);
  _Float16* a_ws = (_Float16*)(ws + 101154816);
  _Float16* bfrag = (_Float16*)(ws + 134873088);          // 3*484*64*4 fp16 = 743,424 B
  unsigned char* mbf = (unsigned char*)(ws + 135616512);  // 64*484*64 u8 = 1,982,464 B

  hipLaunchKernelGGL(k_maskb, dim3((64 * 484 * 64 + 255) / 256), dim3(256), 0, stream, mask, mbf);
  hipLaunchKernelGGL(k_biasf, dim3((3 * 484 * 64 + 255) / 256), dim3(256), 0, stream, rpi, btab, bfrag);
  hipLaunchKernelGGL(k_qkv, dim3(686), dim3(1024), 0, stream, x, Wqkv, bqkv, ls, q_ws, k_ws, v_ws);
  hipLaunchKernelGGL(k_attn, dim3(1536), dim3(384), 0, stream, q_ws, k_ws, v_ws,
                     (const half4*)bfrag, mbf, a_ws);
  hipLaunchKernelGGL(k_proj, dim3(686), dim3(1024), 0, stream, a_ws, Wproj, bproj, out);
}

// Round 2
// 310.723 us; speedup vs baseline: 1.7497x; 1.1180x over previous
//
#include <hip/hip_runtime.h>

typedef __attribute__((ext_vector_type(8))) _Float16 half8;
typedef __attribute__((ext_vector_type(4))) _Float16 half4;
typedef __attribute__((ext_vector_type(4))) float f32x4;
typedef __attribute__((ext_vector_type(2))) unsigned int uint2v;
typedef __attribute__((ext_vector_type(4))) unsigned int uint4v;

__device__ __forceinline__ _Float16 f2h(float f) { return (_Float16)f; }

#define LOG100 4.605170185988091f
#define LOG2E 1.44269504088896f
#define MASKNEG (-144.269504089f)   /* -100 * log2(e), applied pre-exp2 */
#define PADNEG (-100000.0f)         /* pad rows/cols: exp2 -> 0 */

// ---------------- K0a: mask bits in TRANSPOSED MFMA-fragment layout ----------------
// mb[w][qt][kt][lane] u8, bit rr = allowed(R = qt*16+ln15, col = kt*16+quad*4+rr)
__global__ void k_maskb(const float* __restrict__ mask, unsigned char* __restrict__ mb) {
  int tid = blockIdx.x * 256 + threadIdx.x;
  if (tid >= 64 * 484 * 64) return;
  int lane = tid & 63, idx = tid >> 6;
  int kt = idx % 22, t2 = idx / 22;
  int qt = t2 % 22, w = t2 / 22;
  int R = qt * 16 + (lane & 15), col0 = kt * 16 + (lane >> 4) * 4;
  unsigned bits = 0;
#pragma unroll
  for (int rr = 0; rr < 4; rr++) {
    int col = col0 + rr;
    bool pass = true;
    if (R < 343 && col < 343) pass = mask[((size_t)w * 343 + R) * 343 + col] > -50.f;
    bits |= (pass ? 1u : 0u) << rr;
  }
  mb[tid] = (unsigned char)bits;
}

// ---------------- K0b: rel-pos bias, f32, pre-scaled by log2(e) ----
// bf[h][qt][kt][lane][rr] = bias(R=qt*16+ln15, col=kt*16+quad*4+rr)*LOG2E; pads -> PADNEG
__global__ void k_biasf(const int* __restrict__ rpi, const float* __restrict__ table,
                        float* __restrict__ bf) {
  int tid = blockIdx.x * 256 + threadIdx.x;
  if (tid >= 3 * 484 * 64) return;
  int lane = tid & 63, idx = tid >> 6;
  int kt = idx % 22, t2 = idx / 22;
  int qt = t2 % 22, h = t2 / 22;
  int R = qt * 16 + (lane & 15), col0 = kt * 16 + (lane >> 4) * 4;
  f32x4 o;
#pragma unroll
  for (int rr = 0; rr < 4; rr++) {
    int col = col0 + rr;
    o[rr] = (R < 343 && col < 343) ? table[rpi[R * 343 + col] * 3 + h] * LOG2E : PADNEG;
  }
  reinterpret_cast<f32x4*>(bf)[tid] = o;
}

// ---------------- K1: qkv = x @ Wqkv^T + b; normalize q,k; fold scale*log2e into q ----
__global__ __launch_bounds__(1024, 1) void k_qkv(
    const float* __restrict__ x, const float* __restrict__ Wqkv,
    const float* __restrict__ bqkv, const float* __restrict__ ls,
    _Float16* __restrict__ q_ws, _Float16* __restrict__ k_ws, _Float16* __restrict__ v_ws) {
  __shared__ alignas(16) _Float16 Wl[288 * 104];
  const int tid = threadIdx.x;
  for (int i = tid; i < 6912; i += 1024) {
    f32x4 w4 = reinterpret_cast<const f32x4*>(Wqkv)[i];
    int f = i * 4, row = f / 96, col = f - row * 96;
    _Float16* dst = &Wl[row * 104 + col];
    dst[0] = f2h(w4[0]); dst[1] = f2h(w4[1]); dst[2] = f2h(w4[2]); dst[3] = f2h(w4[3]);
  }
  __syncthreads();
  const int lane = tid & 63, wv = tid >> 6;
  const int ln15 = lane & 15, quad = lane >> 4;
  const int rowbase = blockIdx.x * 256 + wv * 16;
  const int arow = rowbase + ln15;

  half8 afr[3];
#pragma unroll
  for (int kt = 0; kt < 3; kt++) {
    const float* xp = x + (size_t)arow * 96 + kt * 32 + quad * 8;
    f32x4 a0 = *reinterpret_cast<const f32x4*>(xp);
    f32x4 a1 = *reinterpret_cast<const f32x4*>(xp + 4);
    half8 a;
    a[0] = f2h(a0[0]); a[1] = f2h(a0[1]); a[2] = f2h(a0[2]); a[3] = f2h(a0[3]);
    a[4] = f2h(a1[0]); a[5] = f2h(a1[1]); a[6] = f2h(a1[2]); a[7] = f2h(a1[3]);
    afr[kt] = a;
  }

  int Bb[4], Nn[4];
#pragma unroll
  for (int rr = 0; rr < 4; rr++) {
    int R = rowbase + quad * 4 + rr;
    Bb[rr] = R / 343;
    Nn[rr] = R - Bb[rr] * 343;
  }

  auto ctile = [&](int nt) -> f32x4 {
    f32x4 c = {0.f, 0.f, 0.f, 0.f};
#pragma unroll
    for (int kt = 0; kt < 3; kt++) {
      half8 b = *reinterpret_cast<const half8*>(&Wl[(nt * 16 + ln15) * 104 + kt * 32 + quad * 8]);
      c = __builtin_amdgcn_mfma_f32_16x16x32_f16(afr[kt], b, c, 0, 0, 0);
    }
    return c;
  };

#pragma unroll
  for (int h = 0; h < 3; h++) {
    float sc = __expf(fminf(ls[h], LOG100)) * LOG2E;  // fold log2(e) for exp2 softmax
    {
      f32x4 c0 = ctile(2 * h), c1 = ctile(2 * h + 1);
      float b0 = bqkv[32 * h + ln15], b1 = bqkv[32 * h + 16 + ln15];
#pragma unroll
      for (int rr = 0; rr < 4; rr++) { c0[rr] += b0; c1[rr] += b1; }
#pragma unroll
      for (int rr = 0; rr < 4; rr++) {
        float s2 = c0[rr] * c0[rr] + c1[rr] * c1[rr];
        s2 += __shfl_xor(s2, 1); s2 += __shfl_xor(s2, 2);
        s2 += __shfl_xor(s2, 4); s2 += __shfl_xor(s2, 8);
        float inv = sc / fmaxf(sqrtf(s2), 1e-12f);
        size_t base = ((size_t)(Bb[rr] * 3 + h) * 343 + Nn[rr]) * 32;
        q_ws[base + ln15] = f2h(c0[rr] * inv);
        q_ws[base + 16 + ln15] = f2h(c1[rr] * inv);
      }
    }
    {
      f32x4 c0 = ctile(6 + 2 * h), c1 = ctile(7 + 2 * h);
      float b0 = bqkv[96 + 32 * h + ln15], b1 = bqkv[96 + 32 * h + 16 + ln15];
#pragma unroll
      for (int rr = 0; rr < 4; rr++) { c0[rr] += b0; c1[rr] += b1; }
#pragma unroll
      for (int rr = 0; rr < 4; rr++) {
        float s2 = c0[rr] * c0[rr] + c1[rr] * c1[rr];
        s2 += __shfl_xor(s2, 1); s2 += __shfl_xor(s2, 2);
        s2 += __shfl_xor(s2, 4); s2 += __shfl_xor(s2, 8);
        float inv = 1.0f / fmaxf(sqrtf(s2), 1e-12f);
        size_t base = ((size_t)(Bb[rr] * 3 + h) * 343 + Nn[rr]) * 32;
        k_ws[base + ln15] = f2h(c0[rr] * inv);
        k_ws[base + 16 + ln15] = f2h(c1[rr] * inv);
      }
    }
    {
      f32x4 c0 = ctile(12 + 2 * h), c1 = ctile(13 + 2 * h);
      float b0 = bqkv[192 + 32 * h + ln15], b1 = bqkv[192 + 32 * h + 16 + ln15];
#pragma unroll
      for (int rr = 0; rr < 4; rr++) {
        size_t base = ((size_t)(Bb[rr] * 3 + h) * 343 + Nn[rr]) * 32;
        v_ws[base + ln15] = f2h(c0[rr] + b0);
        v_ws[base + 16 + ln15] = f2h(c1[rr] + b1);
      }
    }
  }
}

// ---------------- K2: attention per (b,h). 384 threads (6 waves). ----------------
// No-shift one-pass softmax via exp2 (scales folded upstream).
// P redistribution done fully in-register: cvt_pkrtz + permlane32/16_swap (no P LDS,
// no lgkm fence). l accumulated with v_dot2 on the packed fp16 P (numerically
// consistent with the PV numerator). VSTR=360 -> dword stride 20 mod 32 = 2-way (free).
#define KSTR 40
#define VSTR 360
__global__ __launch_bounds__(384, 4) void k_attn(
    const _Float16* __restrict__ q_ws, const _Float16* __restrict__ k_ws,
    const _Float16* __restrict__ v_ws, const float* __restrict__ bfrag,
    const unsigned char* __restrict__ mb, _Float16* __restrict__ a_ws) {
  __shared__ alignas(16) _Float16 Kl[344 * KSTR];   // 27520 B
  __shared__ alignas(16) _Float16 Vt[32 * VSTR];    // 23040 B  (total 50560 -> 3 blk/CU)
  const int blk = blockIdx.x;
  const int b = blk / 3, h = blk - b * 3, w = b & 63;
  const size_t slice = (size_t)(b * 3 + h) * 343 * 32;
  const _Float16* qb = q_ws + slice;
  const _Float16* kb = k_ws + slice;
  const _Float16* vb = v_ws + slice;
  const int tid = threadIdx.x, lane = tid & 63, wv = tid >> 6;
  const int ln15 = lane & 15, quad = lane >> 4;

  // stage K rows (row 343 = zeros, clamp target for pad lanes)
  for (int i = tid; i < 344 * 4; i += 384) {
    int t = i >> 2, c4 = i & 3;
    half8 kv;
    if (t < 343) kv = *reinterpret_cast<const half8*>(kb + t * 32 + c4 * 8);
    else kv = (half8)(_Float16)0.f;
    *reinterpret_cast<half8*>(&Kl[t * KSTR + c4 * 8]) = kv;
  }
  // stage V transposed
  for (int i = tid; i < 1372; i += 384) {
    int n = i >> 2, c4 = i & 3;
    half8 vv = *reinterpret_cast<const half8*>(vb + n * 32 + c4 * 8);
#pragma unroll
    for (int j = 0; j < 8; j++) Vt[(c4 * 8 + j) * VSTR + n] = vv[j];
  }
  for (int i = tid; i < 288; i += 384) {  // zero token-pad cols 343..351
    int d = i / 9, cc = i - d * 9;
    Vt[d * VSTR + 343 + cc] = (_Float16)0.f;
  }
  __syncthreads();

  const float* bfh = bfrag + (size_t)h * 484 * 64 * 4;
  const unsigned char* mbw = mb + (size_t)w * 484 * 64;
  const auto kOnes = __builtin_amdgcn_cvt_pkrtz(1.f, 1.f);

#pragma unroll 1
  for (int qt = wv; qt < 22; qt += 6) {
    const int qbase = qt * 16;
    // Q fragment (MFMA B operand): col = ln15 = q-row
    half8 aq = *reinterpret_cast<const half8*>(qb + (size_t)(qbase + ln15) * 32 + quad * 8);
    const f32x4* bq = reinterpret_cast<const f32x4*>(bfh) + (size_t)qt * 22 * 64 + lane;
    const unsigned char* mq = mbw + (size_t)qt * 22 * 64 + lane;

    f32x4 o0 = {0.f, 0.f, 0.f, 0.f}, o1 = {0.f, 0.f, 0.f, 0.f};  // O^T tiles
    float l0 = 0.f, l1 = 0.f;

    f32x4 ba = bq[0], bb = bq[64];
    unsigned mva = mq[0], mvb = mq[64];
    bq += 128; mq += 128;

#pragma unroll 1
    for (int kc = 0; kc < 11; kc++) {
      // S^T tiles for kt = 2kc, 2kc+1 : mfma(K_frag as A, Q_frag as B)
      int r0 = kc * 32 + ln15;
      int r1 = r0 + 16;
      r1 = (r1 > 343) ? 343 : r1;
      half8 ak0 = *reinterpret_cast<const half8*>(&Kl[r0 * KSTR + quad * 8]);
      half8 ak1 = *reinterpret_cast<const half8*>(&Kl[r1 * KSTR + quad * 8]);
      f32x4 z = {0.f, 0.f, 0.f, 0.f};
      f32x4 s0 = __builtin_amdgcn_mfma_f32_16x16x32_f16(ak0, aq, z, 0, 0, 0);
      f32x4 s1 = __builtin_amdgcn_mfma_f32_16x16x32_f16(ak1, aq, z, 0, 0, 0);

      // prefetch next chunk's bias/mask fragments
      f32x4 nba = ba, nbb = bb;
      unsigned nmva = mva, nmvb = mvb;
      if (kc < 10) {
        nba = bq[0]; nbb = bq[64];
        nmva = mq[0]; nmvb = mq[64];
        bq += 128; mq += 128;
      }

      // exp2(s + bias) then mask-zero (post-exp select: masked contribute exactly 0)
      float p0[4], p1[4];
#pragma unroll
      for (int rr = 0; rr < 4; rr++) {
        float e0 = __builtin_amdgcn_exp2f(s0[rr] + ba[rr]);
        float e1 = __builtin_amdgcn_exp2f(s1[rr] + bb[rr]);
        p0[rr] = ((mva >> rr) & 1u) ? e0 : 0.f;
        p1[rr] = ((mvb >> rr) & 1u) ? e1 : 0.f;
      }
      // pack to fp16 pairs (tokens 4q+2w, 4q+2w+1 per word)
      auto w00 = __builtin_amdgcn_cvt_pkrtz(p0[0], p0[1]);
      auto w01 = __builtin_amdgcn_cvt_pkrtz(p0[2], p0[3]);
      auto w10 = __builtin_amdgcn_cvt_pkrtz(p1[0], p1[1]);
      auto w11 = __builtin_amdgcn_cvt_pkrtz(p1[2], p1[3]);
      // l from the packed (rounded) values -> consistent with PV numerator
      l0 = __builtin_amdgcn_fdot2(w00, kOnes, l0, false);
      l1 = __builtin_amdgcn_fdot2(w01, kOnes, l1, false);
      l0 = __builtin_amdgcn_fdot2(w10, kOnes, l0, false);
      l1 = __builtin_amdgcn_fdot2(w11, kOnes, l1, false);

      // in-register redistribution to PV B-fragment (tokens 8q..8q+7 at lane quad q):
      // permlane32_swap then permlane16_swap gives dst words directly.
      unsigned a0 = __builtin_bit_cast(unsigned int, w00);
      unsigned a1 = __builtin_bit_cast(unsigned int, w01);
      unsigned b0 = __builtin_bit_cast(unsigned int, w10);
      unsigned b1 = __builtin_bit_cast(unsigned int, w11);
      uint2v r32a = __builtin_amdgcn_permlane32_swap(a0, b0, false, false);
      uint2v r32b = __builtin_amdgcn_permlane32_swap(a1, b1, false, false);
      uint2v r16a = __builtin_amdgcn_permlane16_swap(r32a[0], r32a[1], false, false);
      uint2v r16b = __builtin_amdgcn_permlane16_swap(r32b[0], r32b[1], false, false);
      uint4v pw = {r16a[0], r16b[0], r16a[1], r16b[1]};  // {w0,w1,w2,w3}
      half8 pb = __builtin_bit_cast(half8, pw);

      half8 v0 = *reinterpret_cast<const half8*>(&Vt[ln15 * VSTR + kc * 32 + quad * 8]);
      half8 v1 = *reinterpret_cast<const half8*>(&Vt[(16 + ln15) * VSTR + kc * 32 + quad * 8]);
      // O^T += V^T(chunk) . P^T(chunk)
      o0 = __builtin_amdgcn_mfma_f32_16x16x32_f16(v0, pb, o0, 0, 0, 0);
      o1 = __builtin_amdgcn_mfma_f32_16x16x32_f16(v1, pb, o1, 0, 0, 0);

      ba = nba; bb = nbb; mva = nmva; mvb = nmvb;
    }

    // full row sum for qrow = ln15: reduce across the 4 quads
    float l = l0 + l1;
    l += __shfl_xor(l, 16);
    l += __shfl_xor(l, 32);

    const int R = qbase + ln15;
    if (R < 343) {
      float inv = 1.0f / l;
      size_t obase = ((size_t)b * 343 + R) * 96 + h * 32;
      half4 w0, w1;
#pragma unroll
      for (int rr = 0; rr < 4; rr++) {
        w0[rr] = f2h(o0[rr] * inv);
        w1[rr] = f2h(o1[rr] * inv);
      }
      *reinterpret_cast<half4*>(a_ws + obase + quad * 4) = w0;
      *reinterpret_cast<half4*>(a_ws + obase + 16 + quad * 4) = w1;
    }
  }
}

// ---------------- K3: out = attn @ Wproj^T + bproj (fp32 out) ----------------
__global__ __launch_bounds__(1024, 1) void k_proj(
    const _Float16* __restrict__ a_ws, const float* __restrict__ Wproj,
    const float* __restrict__ bproj, float* __restrict__ out) {
  __shared__ alignas(16) _Float16 Wl[96 * 104];
  const int tid = threadIdx.x;
  for (int i = tid; i < 2304; i += 1024) {
    f32x4 w4 = reinterpret_cast<const f32x4*>(Wproj)[i];
    int f = i * 4, row = f / 96, col = f - row * 96;
    _Float16* dst = &Wl[row * 104 + col];
    dst[0] = f2h(w4[0]); dst[1] = f2h(w4[1]); dst[2] = f2h(w4[2]); dst[3] = f2h(w4[3]);
  }
  __syncthreads();
  const int lane = tid & 63, wv = tid >> 6;
  const int ln15 = lane & 15, quad = lane >> 4;
  const int rowbase = blockIdx.x * 256 + wv * 16;
  half8 afr[3];
#pragma unroll
  for (int kt = 0; kt < 3; kt++) {
    afr[kt] = *reinterpret_cast<const half8*>(a_ws + (size_t)(rowbase + ln15) * 96 + kt * 32 + quad * 8);
  }
#pragma unroll
  for (int nt = 0; nt < 6; nt++) {
    f32x4 c = {0.f, 0.f, 0.f, 0.f};
#pragma unroll
    for (int kt = 0; kt < 3; kt++) {
      half8 bfr = *reinterpret_cast<const half8*>(&Wl[(nt * 16 + ln15) * 104 + kt * 32 + quad * 8]);
      c = __builtin_amdgcn_mfma_f32_16x16x32_f16(afr[kt], bfr, c, 0, 0, 0);
    }
    float bb = bproj[nt * 16 + ln15];
#pragma unroll
    for (int rr = 0; rr < 4; rr++) {
      int R = rowbase + quad * 4 + rr;
      out[(size_t)R * 96 + nt * 16 + ln15] = c[rr] + bb;
    }
  }
}

// ---------------- launch ----------------
extern "C" void kernel_launch(void* const* d_in, const int* in_sizes, int n_in,
                              void* d_out, int out_size, void* d_ws, size_t ws_size,
                              hipStream_t stream) {
  const float* x     = (const float*)d_in[0];
  const float* mask  = (const float*)d_in[1];
  const float* Wqkv  = (const float*)d_in[2];
  const float* bqkv  = (const float*)d_in[3];
  const float* Wproj = (const float*)d_in[4];
  const float* bproj = (const float*)d_in[5];
  const float* ls    = (const float*)d_in[6];
  const float* btab  = (const float*)d_in[7];
  const int*   rpi   = (const int*)d_in[8];
  float* out = (float*)d_out;

  char* ws = (char*)d_ws;
  _Float16* q_ws = (_Float16*)(ws);
  _Float16* k_ws = (_Float16*)(ws + 33718272);
  _Float16* v_ws = (_Float16*)(ws + 67436544);
  _Float16* a_ws = (_Float16*)(ws + 101154816);
  float* bfrag = (float*)(ws + 134873088);                // 3*484*64*4 f32 = 1,486,848 B
  unsigned char* mbf = (unsigned char*)(ws + 136359936);  // 64*484*64 u8 = 1,982,464 B

  hipLaunchKernelGGL(k_maskb, dim3((64 * 484 * 64 + 255) / 256), dim3(256), 0, stream, mask, mbf);
  hipLaunchKernelGGL(k_biasf, dim3((3 * 484 * 64 + 255) / 256), dim3(256), 0, stream, rpi, btab, bfrag);
  hipLaunchKernelGGL(k_qkv, dim3(686), dim3(1024), 0, stream, x, Wqkv, bqkv, ls, q_ws, k_ws, v_ws);
  hipLaunchKernelGGL(k_attn, dim3(1536), dim3(384), 0, stream, q_ws, k_ws, v_ws,
                     bfrag, mbf, a_ws);
  hipLaunchKernelGGL(k_proj, dim3(686), dim3(1024), 0, stream, a_ws, Wproj, bproj, out);
}

// Round 7
// 301.707 us; speedup vs baseline: 1.8019x; 1.0299x over previous
//
#include <hip/hip_runtime.h>

typedef __attribute__((ext_vector_type(8))) _Float16 half8;
typedef __attribute__((ext_vector_type(4))) _Float16 half4;
typedef __attribute__((ext_vector_type(2))) __fp16 fp16x2;
typedef __attribute__((ext_vector_type(4))) float f32x4;
typedef __attribute__((ext_vector_type(2))) unsigned int uint2v;
typedef __attribute__((ext_vector_type(4))) unsigned int uint4v;

__device__ __forceinline__ _Float16 f2h(float f) { return (_Float16)f; }

#define LOG100 4.605170185988091f
#define LOG2E 1.44269504088896f
#define PADNEG (-100000.0f) /* pad rows/cols: exp2 -> 0 */

// ---------------- K0a: mask bytes in TRANSPOSED MFMA-fragment layout ----------------
// mb[w][qt][kt][lane] u8, bit rr = allowed(R = qt*16+ln15, col = kt*16+quad*4+rr)
__global__ void k_maskb(const float* __restrict__ mask, unsigned char* __restrict__ mb) {
  int tid = blockIdx.x * 256 + threadIdx.x;
  if (tid >= 64 * 484 * 64) return;
  int lane = tid & 63, idx = tid >> 6;
  int kt = idx % 22, t2 = idx / 22;
  int qt = t2 % 22, w = t2 / 22;
  int R = qt * 16 + (lane & 15), col0 = kt * 16 + (lane >> 4) * 4;
  unsigned bits = 0;
#pragma unroll
  for (int rr = 0; rr < 4; rr++) {
    int col = col0 + rr;
    bool pass = true;
    if (R < 343 && col < 343) pass = mask[((size_t)w * 343 + R) * 343 + col] > -50.f;
    bits |= (pass ? 1u : 0u) << rr;
  }
  mb[tid] = (unsigned char)bits;
}

// ---------------- K0b: rel-pos bias, f32, pre-scaled by log2(e) ----
// bf[h][qt][kt][lane][rr] = bias(R=qt*16+ln15, col=kt*16+quad*4+rr)*LOG2E; pads -> PADNEG
__global__ void k_biasf(const int* __restrict__ rpi, const float* __restrict__ table,
                        float* __restrict__ bf) {
  int tid = blockIdx.x * 256 + threadIdx.x;
  if (tid >= 3 * 484 * 64) return;
  int lane = tid & 63, idx = tid >> 6;
  int kt = idx % 22, t2 = idx / 22;
  int qt = t2 % 22, h = t2 / 22;
  int R = qt * 16 + (lane & 15), col0 = kt * 16 + (lane >> 4) * 4;
  f32x4 o;
#pragma unroll
  for (int rr = 0; rr < 4; rr++) {
    int col = col0 + rr;
    o[rr] = (R < 343 && col < 343) ? table[rpi[R * 343 + col] * 3 + h] * LOG2E : PADNEG;
  }
  reinterpret_cast<f32x4*>(bf)[tid] = o;
}

// ---------------- K1: qkv = x @ Wqkv^T + b; normalize q,k; fold scale*log2e into q ----
__global__ __launch_bounds__(1024, 1) void k_qkv(
    const float* __restrict__ x, const float* __restrict__ Wqkv,
    const float* __restrict__ bqkv, const float* __restrict__ ls,
    _Float16* __restrict__ q_ws, _Float16* __restrict__ k_ws, _Float16* __restrict__ v_ws) {
  __shared__ alignas(16) _Float16 Wl[288 * 104];
  const int tid = threadIdx.x;
  for (int i = tid; i < 6912; i += 1024) {
    f32x4 w4 = reinterpret_cast<const f32x4*>(Wqkv)[i];
    int f = i * 4, row = f / 96, col = f - row * 96;
    _Float16* dst = &Wl[row * 104 + col];
    dst[0] = f2h(w4[0]); dst[1] = f2h(w4[1]); dst[2] = f2h(w4[2]); dst[3] = f2h(w4[3]);
  }
  __syncthreads();
  const int lane = tid & 63, wv = tid >> 6;
  const int ln15 = lane & 15, quad = lane >> 4;
  const int rowbase = blockIdx.x * 256 + wv * 16;
  const int arow = rowbase + ln15;

  half8 afr[3];
#pragma unroll
  for (int kt = 0; kt < 3; kt++) {
    const float* xp = x + (size_t)arow * 96 + kt * 32 + quad * 8;
    f32x4 a0 = *reinterpret_cast<const f32x4*>(xp);
    f32x4 a1 = *reinterpret_cast<const f32x4*>(xp + 4);
    half8 a;
    a[0] = f2h(a0[0]); a[1] = f2h(a0[1]); a[2] = f2h(a0[2]); a[3] = f2h(a0[3]);
    a[4] = f2h(a1[0]); a[5] = f2h(a1[1]); a[6] = f2h(a1[2]); a[7] = f2h(a1[3]);
    afr[kt] = a;
  }

  int Bb[4], Nn[4];
#pragma unroll
  for (int rr = 0; rr < 4; rr++) {
    int R = rowbase + quad * 4 + rr;
    Bb[rr] = R / 343;
    Nn[rr] = R - Bb[rr] * 343;
  }

  auto ctile = [&](int nt) -> f32x4 {
    f32x4 c = {0.f, 0.f, 0.f, 0.f};
#pragma unroll
    for (int kt = 0; kt < 3; kt++) {
      half8 b = *reinterpret_cast<const half8*>(&Wl[(nt * 16 + ln15) * 104 + kt * 32 + quad * 8]);
      c = __builtin_amdgcn_mfma_f32_16x16x32_f16(afr[kt], b, c, 0, 0, 0);
    }
    return c;
  };

#pragma unroll
  for (int h = 0; h < 3; h++) {
    float sc = __expf(fminf(ls[h], LOG100)) * LOG2E;  // fold log2(e) for exp2 softmax
    {
      f32x4 c0 = ctile(2 * h), c1 = ctile(2 * h + 1);
      float b0 = bqkv[32 * h + ln15], b1 = bqkv[32 * h + 16 + ln15];
#pragma unroll
      for (int rr = 0; rr < 4; rr++) { c0[rr] += b0; c1[rr] += b1; }
#pragma unroll
      for (int rr = 0; rr < 4; rr++) {
        float s2 = c0[rr] * c0[rr] + c1[rr] * c1[rr];
        s2 += __shfl_xor(s2, 1); s2 += __shfl_xor(s2, 2);
        s2 += __shfl_xor(s2, 4); s2 += __shfl_xor(s2, 8);
        float inv = sc / fmaxf(sqrtf(s2), 1e-12f);
        size_t base = ((size_t)(Bb[rr] * 3 + h) * 343 + Nn[rr]) * 32;
        q_ws[base + ln15] = f2h(c0[rr] * inv);
        q_ws[base + 16 + ln15] = f2h(c1[rr] * inv);
      }
    }
    {
      f32x4 c0 = ctile(6 + 2 * h), c1 = ctile(7 + 2 * h);
      float b0 = bqkv[96 + 32 * h + ln15], b1 = bqkv[96 + 32 * h + 16 + ln15];
#pragma unroll
      for (int rr = 0; rr < 4; rr++) { c0[rr] += b0; c1[rr] += b1; }
#pragma unroll
      for (int rr = 0; rr < 4; rr++) {
        float s2 = c0[rr] * c0[rr] + c1[rr] * c1[rr];
        s2 += __shfl_xor(s2, 1); s2 += __shfl_xor(s2, 2);
        s2 += __shfl_xor(s2, 4); s2 += __shfl_xor(s2, 8);
        float inv = 1.0f / fmaxf(sqrtf(s2), 1e-12f);
        size_t base = ((size_t)(Bb[rr] * 3 + h) * 343 + Nn[rr]) * 32;
        k_ws[base + ln15] = f2h(c0[rr] * inv);
        k_ws[base + 16 + ln15] = f2h(c1[rr] * inv);
      }
    }
    {
      f32x4 c0 = ctile(12 + 2 * h), c1 = ctile(13 + 2 * h);
      float b0 = bqkv[192 + 32 * h + ln15], b1 = bqkv[192 + 32 * h + 16 + ln15];
#pragma unroll
      for (int rr = 0; rr < 4; rr++) {
        size_t base = ((size_t)(Bb[rr] * 3 + h) * 343 + Nn[rr]) * 32;
        v_ws[base + ln15] = f2h(c0[rr] + b0);
        v_ws[base + 16 + ln15] = f2h(c1[rr] + b1);
      }
    }
  }
}

// ---------------- K2: attention per (b,h). 384 threads (6 waves). ----------------
// EXACT round-2 verified structure (rolled kc loop, unroll 1, prefetch vars) with
// two register-only deltas: (1) bias fragment fed as the QK^T MFMA C-operand
// (removes 8 v_add_f32/kc, exp2 starts directly on the MFMA result);
// (2) l split into 4 independent fdot2 accumulators (halved reduce chain).
#define KSTR 40
#define VSTR 360
__global__ __launch_bounds__(384, 4) void k_attn(
    const _Float16* __restrict__ q_ws, const _Float16* __restrict__ k_ws,
    const _Float16* __restrict__ v_ws, const float* __restrict__ bfrag,
    const unsigned char* __restrict__ mb, _Float16* __restrict__ a_ws) {
  __shared__ alignas(16) _Float16 Kl[344 * KSTR];   // 27520 B
  __shared__ alignas(16) _Float16 Vt[32 * VSTR];    // 23040 B  (total 50560)
  const int blk = blockIdx.x;
  const int b = blk / 3, h = blk - b * 3, w = b & 63;
  const size_t slice = (size_t)(b * 3 + h) * 343 * 32;
  const _Float16* qb = q_ws + slice;
  const _Float16* kb = k_ws + slice;
  const _Float16* vb = v_ws + slice;
  const int tid = threadIdx.x, lane = tid & 63, wv = tid >> 6;
  const int ln15 = lane & 15, quad = lane >> 4;

  // stage K rows (row 343 = zeros, clamp target for pad lanes)
  for (int i = tid; i < 344 * 4; i += 384) {
    int t = i >> 2, c4 = i & 3;
    half8 kv;
    if (t < 343) kv = *reinterpret_cast<const half8*>(kb + t * 32 + c4 * 8);
    else kv = (half8)(_Float16)0.f;
    *reinterpret_cast<half8*>(&Kl[t * KSTR + c4 * 8]) = kv;
  }
  // stage V transposed
  for (int i = tid; i < 1372; i += 384) {
    int n = i >> 2, c4 = i & 3;
    half8 vv = *reinterpret_cast<const half8*>(vb + n * 32 + c4 * 8);
#pragma unroll
    for (int j = 0; j < 8; j++) Vt[(c4 * 8 + j) * VSTR + n] = vv[j];
  }
  for (int i = tid; i < 288; i += 384) {  // zero token-pad cols 343..351
    int d = i / 9, cc = i - d * 9;
    Vt[d * VSTR + 343 + cc] = (_Float16)0.f;
  }
  __syncthreads();

  const float* bfh = bfrag + (size_t)h * 484 * 64 * 4;
  const unsigned char* mbw = mb + (size_t)w * 484 * 64;
  const fp16x2 kOnes = __builtin_amdgcn_cvt_pkrtz(1.f, 1.f);

#pragma unroll 1
  for (int qt = wv; qt < 22; qt += 6) {
    const int qbase = qt * 16;
    // Q fragment (MFMA B operand): col = ln15 = q-row
    half8 aq = *reinterpret_cast<const half8*>(qb + (size_t)(qbase + ln15) * 32 + quad * 8);
    const f32x4* bq = reinterpret_cast<const f32x4*>(bfh) + (size_t)qt * 22 * 64 + lane;
    const unsigned char* mq = mbw + (size_t)qt * 22 * 64 + lane;

    f32x4 o0 = {0.f, 0.f, 0.f, 0.f}, o1 = {0.f, 0.f, 0.f, 0.f};  // O^T tiles
    float l00 = 0.f, l01 = 0.f, l10 = 0.f, l11 = 0.f;

    f32x4 ba = bq[0], bb = bq[64];
    unsigned mva = mq[0], mvb = mq[64];
    bq += 128; mq += 128;

#pragma unroll 1
    for (int kc = 0; kc < 11; kc++) {
      // S^T tiles for kt = 2kc, 2kc+1 : mfma(K_frag as A, Q_frag as B, C = bias)
      int r0 = kc * 32 + ln15;
      int r1 = r0 + 16;
      r1 = (r1 > 343) ? 343 : r1;
      half8 ak0 = *reinterpret_cast<const half8*>(&Kl[r0 * KSTR + quad * 8]);
      half8 ak1 = *reinterpret_cast<const half8*>(&Kl[r1 * KSTR + quad * 8]);
      f32x4 s0 = __builtin_amdgcn_mfma_f32_16x16x32_f16(ak0, aq, ba, 0, 0, 0);
      f32x4 s1 = __builtin_amdgcn_mfma_f32_16x16x32_f16(ak1, aq, bb, 0, 0, 0);

      // prefetch next chunk's bias/mask fragments
      f32x4 nba = ba, nbb = bb;
      unsigned nmva = mva, nmvb = mvb;
      if (kc < 10) {
        nba = bq[0]; nbb = bq[64];
        nmva = mq[0]; nmvb = mq[64];
        bq += 128; mq += 128;
      }

      // exp2(s) (bias already inside) then mask-select 0; pads: bias=PADNEG -> 0
      float e00 = __builtin_amdgcn_exp2f(s0[0]);
      float e01 = __builtin_amdgcn_exp2f(s0[1]);
      float e02 = __builtin_amdgcn_exp2f(s0[2]);
      float e03 = __builtin_amdgcn_exp2f(s0[3]);
      float e10 = __builtin_amdgcn_exp2f(s1[0]);
      float e11 = __builtin_amdgcn_exp2f(s1[1]);
      float e12 = __builtin_amdgcn_exp2f(s1[2]);
      float e13 = __builtin_amdgcn_exp2f(s1[3]);
      float p00 = ((mva >> 0) & 1u) ? e00 : 0.f;
      float p01 = ((mva >> 1) & 1u) ? e01 : 0.f;
      float p02 = ((mva >> 2) & 1u) ? e02 : 0.f;
      float p03 = ((mva >> 3) & 1u) ? e03 : 0.f;
      float p10 = ((mvb >> 0) & 1u) ? e10 : 0.f;
      float p11 = ((mvb >> 1) & 1u) ? e11 : 0.f;
      float p12 = ((mvb >> 2) & 1u) ? e12 : 0.f;
      float p13 = ((mvb >> 3) & 1u) ? e13 : 0.f;

      // pack to fp16 pairs
      fp16x2 w00 = __builtin_amdgcn_cvt_pkrtz(p00, p01);
      fp16x2 w01 = __builtin_amdgcn_cvt_pkrtz(p02, p03);
      fp16x2 w10 = __builtin_amdgcn_cvt_pkrtz(p10, p11);
      fp16x2 w11 = __builtin_amdgcn_cvt_pkrtz(p12, p13);

      // l from the packed (rounded) values -> consistent with PV numerator
      l00 = __builtin_amdgcn_fdot2(w00, kOnes, l00, false);
      l01 = __builtin_amdgcn_fdot2(w01, kOnes, l01, false);
      l10 = __builtin_amdgcn_fdot2(w10, kOnes, l10, false);
      l11 = __builtin_amdgcn_fdot2(w11, kOnes, l11, false);

      // in-register redistribution to PV B-fragment (tokens 8q..8q+7 at lane quad q)
      unsigned a0 = __builtin_bit_cast(unsigned int, w00);
      unsigned a1 = __builtin_bit_cast(unsigned int, w01);
      unsigned b0 = __builtin_bit_cast(unsigned int, w10);
      unsigned b1 = __builtin_bit_cast(unsigned int, w11);
      uint2v r32a = __builtin_amdgcn_permlane32_swap(a0, b0, false, false);
      uint2v r32b = __builtin_amdgcn_permlane32_swap(a1, b1, false, false);
      uint2v r16a = __builtin_amdgcn_permlane16_swap(r32a[0], r32a[1], false, false);
      uint2v r16b = __builtin_amdgcn_permlane16_swap(r32b[0], r32b[1], false, false);
      uint4v pw = {r16a[0], r16b[0], r16a[1], r16b[1]};
      half8 pb = __builtin_bit_cast(half8, pw);

      half8 v0 = *reinterpret_cast<const half8*>(&Vt[ln15 * VSTR + kc * 32 + quad * 8]);
      half8 v1 = *reinterpret_cast<const half8*>(&Vt[(16 + ln15) * VSTR + kc * 32 + quad * 8]);
      // O^T += V^T(chunk) . P^T(chunk)
      o0 = __builtin_amdgcn_mfma_f32_16x16x32_f16(v0, pb, o0, 0, 0, 0);
      o1 = __builtin_amdgcn_mfma_f32_16x16x32_f16(v1, pb, o1, 0, 0, 0);

      ba = nba; bb = nbb; mva = nmva; mvb = nmvb;
    }

    // full row sum for qrow = ln15: reduce across the 4 quads
    float l = (l00 + l01) + (l10 + l11);
    l += __shfl_xor(l, 16);
    l += __shfl_xor(l, 32);

    const int R = qbase + ln15;
    if (R < 343) {
      float inv = 1.0f / l;
      size_t obase = ((size_t)b * 343 + R) * 96 + h * 32;
      half4 w0, w1;
#pragma unroll
      for (int rr = 0; rr < 4; rr++) {
        w0[rr] = f2h(o0[rr] * inv);
        w1[rr] = f2h(o1[rr] * inv);
      }
      *reinterpret_cast<half4*>(a_ws + obase + quad * 4) = w0;
      *reinterpret_cast<half4*>(a_ws + obase + 16 + quad * 4) = w1;
    }
  }
}

// ---------------- K3: out = attn @ Wproj^T + bproj (fp32 out) ----------------
__global__ __launch_bounds__(1024, 1) void k_proj(
    const _Float16* __restrict__ a_ws, const float* __restrict__ Wproj,
    const float* __restrict__ bproj, float* __restrict__ out) {
  __shared__ alignas(16) _Float16 Wl[96 * 104];
  const int tid = threadIdx.x;
  for (int i = tid; i < 2304; i += 1024) {
    f32x4 w4 = reinterpret_cast<const f32x4*>(Wproj)[i];
    int f = i * 4, row = f / 96, col = f - row * 96;
    _Float16* dst = &Wl[row * 104 + col];
    dst[0] = f2h(w4[0]); dst[1] = f2h(w4[1]); dst[2] = f2h(w4[2]); dst[3] = f2h(w4[3]);
  }
  __syncthreads();
  const int lane = tid & 63, wv = tid >> 6;
  const int ln15 = lane & 15, quad = lane >> 4;
  const int rowbase = blockIdx.x * 256 + wv * 16;
  half8 afr[3];
#pragma unroll
  for (int kt = 0; kt < 3; kt++) {
    afr[kt] = *reinterpret_cast<const half8*>(a_ws + (size_t)(rowbase + ln15) * 96 + kt * 32 + quad * 8);
  }
#pragma unroll
  for (int nt = 0; nt < 6; nt++) {
    f32x4 c = {0.f, 0.f, 0.f, 0.f};
#pragma unroll
    for (int kt = 0; kt < 3; kt++) {
      half8 bfr = *reinterpret_cast<const half8*>(&Wl[(nt * 16 + ln15) * 104 + kt * 32 + quad * 8]);
      c = __builtin_amdgcn_mfma_f32_16x16x32_f16(afr[kt], bfr, c, 0, 0, 0);
    }
    float bb = bproj[nt * 16 + ln15];
#pragma unroll
    for (int rr = 0; rr < 4; rr++) {
      int R = rowbase + quad * 4 + rr;
      out[(size_t)R * 96 + nt * 16 + ln15] = c[rr] + bb;
    }
  }
}

// ---------------- launch ----------------
extern "C" void kernel_launch(void* const* d_in, const int* in_sizes, int n_in,
                              void* d_out, int out_size, void* d_ws, size_t ws_size,
                              hipStream_t stream) {
  const float* x     = (const float*)d_in[0];
  const float* mask  = (const float*)d_in[1];
  const float* Wqkv  = (const float*)d_in[2];
  const float* bqkv  = (const float*)d_in[3];
  const float* Wproj = (const float*)d_in[4];
  const float* bproj = (const float*)d_in[5];
  const float* ls    = (const float*)d_in[6];
  const float* btab  = (const float*)d_in[7];
  const int*   rpi   = (const int*)d_in[8];
  float* out = (float*)d_out;

  char* ws = (char*)d_ws;
  _Float16* q_ws = (_Float16*)(ws);
  _Float16* k_ws = (_Float16*)(ws + 33718272);
  _Float16* v_ws = (_Float16*)(ws + 67436544);
  _Float16* a_ws = (_Float16*)(ws + 101154816);
  float* bfrag = (float*)(ws + 134873088);                // 3*484*64*4 f32 = 1,486,848 B
  unsigned char* mbf = (unsigned char*)(ws + 136359936);  // 64*484*64 u8 = 1,982,464 B
  // end = 138,342,400 B (verified in round 2)

  hipLaunchKernelGGL(k_maskb, dim3((64 * 484 * 64 + 255) / 256), dim3(256), 0, stream, mask, mbf);
  hipLaunchKernelGGL(k_biasf, dim3((3 * 484 * 64 + 255) / 256), dim3(256), 0, stream, rpi, btab, bfrag);
  hipLaunchKernelGGL(k_qkv, dim3(686), dim3(1024), 0, stream, x, Wqkv, bqkv, ls, q_ws, k_ws, v_ws);
  hipLaunchKernelGGL(k_attn, dim3(1536), dim3(384), 0, stream, q_ws, k_ws, v_ws,
                     bfrag, mbf, a_ws);
  hipLaunchKernelGGL(k_proj, dim3(686), dim3(1024), 0, stream, a_ws, Wproj, bproj, out);
}

// Round 8
// 285.390 us; speedup vs baseline: 1.9050x; 1.0572x over previous
//
#include <hip/hip_runtime.h>

typedef __attribute__((ext_vector_type(8))) _Float16 half8;
typedef __attribute__((ext_vector_type(4))) _Float16 half4;
typedef __attribute__((ext_vector_type(2))) __fp16 fp16x2;
typedef __attribute__((ext_vector_type(4))) float f32x4;
typedef __attribute__((ext_vector_type(2))) unsigned int uint2v;
typedef __attribute__((ext_vector_type(4))) unsigned int uint4v;

__device__ __forceinline__ _Float16 f2h(float f) { return (_Float16)f; }

#define LOG100 4.605170185988091f
#define LOG2E 1.44269504088896f
#define PADNEG (-100000.0f) /* pad rows/cols: exp2 -> 0 */

// ---------------- K_prep: mask bytes + bias fragments in one launch ----------------
// Part A (blocks [0,7744)): mb[w][qt][kt][lane] u8,
//   bit rr = allowed(R = qt*16+ln15, col = kt*16+quad*4+rr); pads -> 1 (bias kills them)
// Part B (blocks [7744,8107)): bf[h][qt][kt][lane][rr] =
//   bias(R,col)*LOG2E; pads -> PADNEG
#define MASK_BLOCKS 7744 /* 64*484*64/256 exact */
#define BIAS_BLOCKS 363  /* 3*484*64/256 exact */
__global__ void k_prep(const float* __restrict__ mask, const int* __restrict__ rpi,
                       const float* __restrict__ table,
                       unsigned char* __restrict__ mb, float* __restrict__ bf) {
  if (blockIdx.x < MASK_BLOCKS) {
    int tid = blockIdx.x * 256 + threadIdx.x;
    if (tid >= 64 * 484 * 64) return;
    int lane = tid & 63, idx = tid >> 6;
    int kt = idx % 22, t2 = idx / 22;
    int qt = t2 % 22, w = t2 / 22;
    int R = qt * 16 + (lane & 15), col0 = kt * 16 + (lane >> 4) * 4;
    unsigned bits = 0;
#pragma unroll
    for (int rr = 0; rr < 4; rr++) {
      int col = col0 + rr;
      bool pass = true;
      if (R < 343 && col < 343) pass = mask[((size_t)w * 343 + R) * 343 + col] > -50.f;
      bits |= (pass ? 1u : 0u) << rr;
    }
    mb[tid] = (unsigned char)bits;
  } else {
    int tid = (blockIdx.x - MASK_BLOCKS) * 256 + threadIdx.x;
    if (tid >= 3 * 484 * 64) return;
    int lane = tid & 63, idx = tid >> 6;
    int kt = idx % 22, t2 = idx / 22;
    int qt = t2 % 22, h = t2 / 22;
    int R = qt * 16 + (lane & 15), col0 = kt * 16 + (lane >> 4) * 4;
    f32x4 o;
#pragma unroll
    for (int rr = 0; rr < 4; rr++) {
      int col = col0 + rr;
      o[rr] = (R < 343 && col < 343) ? table[rpi[R * 343 + col] * 3 + h] * LOG2E : PADNEG;
    }
    reinterpret_cast<f32x4*>(bf)[tid] = o;
  }
}

// ---------------- K1: qkv = x @ Wqkv^T + b; normalize q,k; fold scale*log2e into q ----
__global__ __launch_bounds__(1024, 1) void k_qkv(
    const float* __restrict__ x, const float* __restrict__ Wqkv,
    const float* __restrict__ bqkv, const float* __restrict__ ls,
    _Float16* __restrict__ q_ws, _Float16* __restrict__ k_ws, _Float16* __restrict__ v_ws) {
  __shared__ alignas(16) _Float16 Wl[288 * 104];
  const int tid = threadIdx.x;
  for (int i = tid; i < 6912; i += 1024) {
    f32x4 w4 = reinterpret_cast<const f32x4*>(Wqkv)[i];
    int f = i * 4, row = f / 96, col = f - row * 96;
    _Float16* dst = &Wl[row * 104 + col];
    dst[0] = f2h(w4[0]); dst[1] = f2h(w4[1]); dst[2] = f2h(w4[2]); dst[3] = f2h(w4[3]);
  }
  __syncthreads();
  const int lane = tid & 63, wv = tid >> 6;
  const int ln15 = lane & 15, quad = lane >> 4;
  const int rowbase = blockIdx.x * 256 + wv * 16;
  const int arow = rowbase + ln15;

  half8 afr[3];
#pragma unroll
  for (int kt = 0; kt < 3; kt++) {
    const float* xp = x + (size_t)arow * 96 + kt * 32 + quad * 8;
    f32x4 a0 = *reinterpret_cast<const f32x4*>(xp);
    f32x4 a1 = *reinterpret_cast<const f32x4*>(xp + 4);
    half8 a;
    a[0] = f2h(a0[0]); a[1] = f2h(a0[1]); a[2] = f2h(a0[2]); a[3] = f2h(a0[3]);
    a[4] = f2h(a1[0]); a[5] = f2h(a1[1]); a[6] = f2h(a1[2]); a[7] = f2h(a1[3]);
    afr[kt] = a;
  }

  int Bb[4], Nn[4];
#pragma unroll
  for (int rr = 0; rr < 4; rr++) {
    int R = rowbase + quad * 4 + rr;
    Bb[rr] = R / 343;
    Nn[rr] = R - Bb[rr] * 343;
  }

  auto ctile = [&](int nt) -> f32x4 {
    f32x4 c = {0.f, 0.f, 0.f, 0.f};
#pragma unroll
    for (int kt = 0; kt < 3; kt++) {
      half8 b = *reinterpret_cast<const half8*>(&Wl[(nt * 16 + ln15) * 104 + kt * 32 + quad * 8]);
      c = __builtin_amdgcn_mfma_f32_16x16x32_f16(afr[kt], b, c, 0, 0, 0);
    }
    return c;
  };

#pragma unroll
  for (int h = 0; h < 3; h++) {
    float sc = __expf(fminf(ls[h], LOG100)) * LOG2E;  // fold log2(e) for exp2 softmax
    {
      f32x4 c0 = ctile(2 * h), c1 = ctile(2 * h + 1);
      float b0 = bqkv[32 * h + ln15], b1 = bqkv[32 * h + 16 + ln15];
#pragma unroll
      for (int rr = 0; rr < 4; rr++) { c0[rr] += b0; c1[rr] += b1; }
#pragma unroll
      for (int rr = 0; rr < 4; rr++) {
        float s2 = c0[rr] * c0[rr] + c1[rr] * c1[rr];
        s2 += __shfl_xor(s2, 1); s2 += __shfl_xor(s2, 2);
        s2 += __shfl_xor(s2, 4); s2 += __shfl_xor(s2, 8);
        float inv = sc / fmaxf(sqrtf(s2), 1e-12f);
        size_t base = ((size_t)(Bb[rr] * 3 + h) * 343 + Nn[rr]) * 32;
        q_ws[base + ln15] = f2h(c0[rr] * inv);
        q_ws[base + 16 + ln15] = f2h(c1[rr] * inv);
      }
    }
    {
      f32x4 c0 = ctile(6 + 2 * h), c1 = ctile(7 + 2 * h);
      float b0 = bqkv[96 + 32 * h + ln15], b1 = bqkv[96 + 32 * h + 16 + ln15];
#pragma unroll
      for (int rr = 0; rr < 4; rr++) { c0[rr] += b0; c1[rr] += b1; }
#pragma unroll
      for (int rr = 0; rr < 4; rr++) {
        float s2 = c0[rr] * c0[rr] + c1[rr] * c1[rr];
        s2 += __shfl_xor(s2, 1); s2 += __shfl_xor(s2, 2);
        s2 += __shfl_xor(s2, 4); s2 += __shfl_xor(s2, 8);
        float inv = 1.0f / fmaxf(sqrtf(s2), 1e-12f);
        size_t base = ((size_t)(Bb[rr] * 3 + h) * 343 + Nn[rr]) * 32;
        k_ws[base + ln15] = f2h(c0[rr] * inv);
        k_ws[base + 16 + ln15] = f2h(c1[rr] * inv);
      }
    }
    {
      f32x4 c0 = ctile(12 + 2 * h), c1 = ctile(13 + 2 * h);
      float b0 = bqkv[192 + 32 * h + ln15], b1 = bqkv[192 + 32 * h + 16 + ln15];
#pragma unroll
      for (int rr = 0; rr < 4; rr++) {
        size_t base = ((size_t)(Bb[rr] * 3 + h) * 343 + Nn[rr]) * 32;
        v_ws[base + ln15] = f2h(c0[rr] + b0);
        v_ws[base + 16 + ln15] = f2h(c1[rr] + b1);
      }
    }
  }
}

// ---------------- K2: attention per (b,h). 512 threads (8 waves). ----------------
// Round-7 verified math (bias as QK^T MFMA C-operand, exp2 no-shift softmax,
// bit-test mask select, in-register P redistribution via permlane32/16_swap,
// 4 fdot2 accumulators). Delta vs r7: 8 waves/block and qt += 8 -> per-block
// critical path 4 -> 3 serial qt tiles, resident waves/CU 18 -> 24 (3 blk/CU:
// 3*50688 B = 152 KB < 160 KB LDS, 3*512 = 1536 <= 2048 threads).
#define KSTR 40
#define VSTR 360
__global__ __launch_bounds__(512, 3) void k_attn(
    const _Float16* __restrict__ q_ws, const _Float16* __restrict__ k_ws,
    const _Float16* __restrict__ v_ws, const float* __restrict__ bfrag,
    const unsigned char* __restrict__ mb, _Float16* __restrict__ a_ws) {
  __shared__ alignas(16) _Float16 Kl[344 * KSTR];   // 27520 B
  __shared__ alignas(16) _Float16 Vt[32 * VSTR];    // 23040 B  (total 50560)
  const int blk = blockIdx.x;
  const int b = blk / 3, h = blk - b * 3, w = b & 63;
  const size_t slice = (size_t)(b * 3 + h) * 343 * 32;
  const _Float16* qb = q_ws + slice;
  const _Float16* kb = k_ws + slice;
  const _Float16* vb = v_ws + slice;
  const int tid = threadIdx.x, lane = tid & 63, wv = tid >> 6;
  const int ln15 = lane & 15, quad = lane >> 4;

  // stage K rows (row 343 = zeros, clamp target for pad lanes)
  for (int i = tid; i < 344 * 4; i += 512) {
    int t = i >> 2, c4 = i & 3;
    half8 kv;
    if (t < 343) kv = *reinterpret_cast<const half8*>(kb + t * 32 + c4 * 8);
    else kv = (half8)(_Float16)0.f;
    *reinterpret_cast<half8*>(&Kl[t * KSTR + c4 * 8]) = kv;
  }
  // stage V transposed
  for (int i = tid; i < 1372; i += 512) {
    int n = i >> 2, c4 = i & 3;
    half8 vv = *reinterpret_cast<const half8*>(vb + n * 32 + c4 * 8);
#pragma unroll
    for (int j = 0; j < 8; j++) Vt[(c4 * 8 + j) * VSTR + n] = vv[j];
  }
  for (int i = tid; i < 288; i += 512) {  // zero token-pad cols 343..351
    int d = i / 9, cc = i - d * 9;
    Vt[d * VSTR + 343 + cc] = (_Float16)0.f;
  }
  __syncthreads();

  const float* bfh = bfrag + (size_t)h * 484 * 64 * 4;
  const unsigned char* mbw = mb + (size_t)w * 484 * 64;
  const fp16x2 kOnes = __builtin_amdgcn_cvt_pkrtz(1.f, 1.f);

#pragma unroll 1
  for (int qt = wv; qt < 22; qt += 8) {
    const int qbase = qt * 16;
    // Q fragment (MFMA B operand): col = ln15 = q-row
    half8 aq = *reinterpret_cast<const half8*>(qb + (size_t)(qbase + ln15) * 32 + quad * 8);
    const f32x4* bq = reinterpret_cast<const f32x4*>(bfh) + (size_t)qt * 22 * 64 + lane;
    const unsigned char* mq = mbw + (size_t)qt * 22 * 64 + lane;

    f32x4 o0 = {0.f, 0.f, 0.f, 0.f}, o1 = {0.f, 0.f, 0.f, 0.f};  // O^T tiles
    float l00 = 0.f, l01 = 0.f, l10 = 0.f, l11 = 0.f;

    f32x4 ba = bq[0], bb = bq[64];
    unsigned mva = mq[0], mvb = mq[64];
    bq += 128; mq += 128;

#pragma unroll 1
    for (int kc = 0; kc < 11; kc++) {
      // S^T tiles for kt = 2kc, 2kc+1 : mfma(K_frag as A, Q_frag as B, C = bias)
      int r0 = kc * 32 + ln15;
      int r1 = r0 + 16;
      r1 = (r1 > 343) ? 343 : r1;
      half8 ak0 = *reinterpret_cast<const half8*>(&Kl[r0 * KSTR + quad * 8]);
      half8 ak1 = *reinterpret_cast<const half8*>(&Kl[r1 * KSTR + quad * 8]);
      f32x4 s0 = __builtin_amdgcn_mfma_f32_16x16x32_f16(ak0, aq, ba, 0, 0, 0);
      f32x4 s1 = __builtin_amdgcn_mfma_f32_16x16x32_f16(ak1, aq, bb, 0, 0, 0);

      // prefetch next chunk's bias/mask fragments
      f32x4 nba = ba, nbb = bb;
      unsigned nmva = mva, nmvb = mvb;
      if (kc < 10) {
        nba = bq[0]; nbb = bq[64];
        nmva = mq[0]; nmvb = mq[64];
        bq += 128; mq += 128;
      }

      // exp2(s) (bias already inside) then mask-select 0; pads: bias=PADNEG -> 0
      float e00 = __builtin_amdgcn_exp2f(s0[0]);
      float e01 = __builtin_amdgcn_exp2f(s0[1]);
      float e02 = __builtin_amdgcn_exp2f(s0[2]);
      float e03 = __builtin_amdgcn_exp2f(s0[3]);
      float e10 = __builtin_amdgcn_exp2f(s1[0]);
      float e11 = __builtin_amdgcn_exp2f(s1[1]);
      float e12 = __builtin_amdgcn_exp2f(s1[2]);
      float e13 = __builtin_amdgcn_exp2f(s1[3]);
      float p00 = ((mva >> 0) & 1u) ? e00 : 0.f;
      float p01 = ((mva >> 1) & 1u) ? e01 : 0.f;
      float p02 = ((mva >> 2) & 1u) ? e02 : 0.f;
      float p03 = ((mva >> 3) & 1u) ? e03 : 0.f;
      float p10 = ((mvb >> 0) & 1u) ? e10 : 0.f;
      float p11 = ((mvb >> 1) & 1u) ? e11 : 0.f;
      float p12 = ((mvb >> 2) & 1u) ? e12 : 0.f;
      float p13 = ((mvb >> 3) & 1u) ? e13 : 0.f;

      // pack to fp16 pairs
      fp16x2 w00 = __builtin_amdgcn_cvt_pkrtz(p00, p01);
      fp16x2 w01 = __builtin_amdgcn_cvt_pkrtz(p02, p03);
      fp16x2 w10 = __builtin_amdgcn_cvt_pkrtz(p10, p11);
      fp16x2 w11 = __builtin_amdgcn_cvt_pkrtz(p12, p13);

      // l from the packed (rounded) values -> consistent with PV numerator
      l00 = __builtin_amdgcn_fdot2(w00, kOnes, l00, false);
      l01 = __builtin_amdgcn_fdot2(w01, kOnes, l01, false);
      l10 = __builtin_amdgcn_fdot2(w10, kOnes, l10, false);
      l11 = __builtin_amdgcn_fdot2(w11, kOnes, l11, false);

      // in-register redistribution to PV B-fragment (tokens 8q..8q+7 at lane quad q)
      unsigned a0 = __builtin_bit_cast(unsigned int, w00);
      unsigned a1 = __builtin_bit_cast(unsigned int, w01);
      unsigned b0 = __builtin_bit_cast(unsigned int, w10);
      unsigned b1 = __builtin_bit_cast(unsigned int, w11);
      uint2v r32a = __builtin_amdgcn_permlane32_swap(a0, b0, false, false);
      uint2v r32b = __builtin_amdgcn_permlane32_swap(a1, b1, false, false);
      uint2v r16a = __builtin_amdgcn_permlane16_swap(r32a[0], r32a[1], false, false);
      uint2v r16b = __builtin_amdgcn_permlane16_swap(r32b[0], r32b[1], false, false);
      uint4v pw = {r16a[0], r16b[0], r16a[1], r16b[1]};
      half8 pb = __builtin_bit_cast(half8, pw);

      half8 v0 = *reinterpret_cast<const half8*>(&Vt[ln15 * VSTR + kc * 32 + quad * 8]);
      half8 v1 = *reinterpret_cast<const half8*>(&Vt[(16 + ln15) * VSTR + kc * 32 + quad * 8]);
      // O^T += V^T(chunk) . P^T(chunk)
      o0 = __builtin_amdgcn_mfma_f32_16x16x32_f16(v0, pb, o0, 0, 0, 0);
      o1 = __builtin_amdgcn_mfma_f32_16x16x32_f16(v1, pb, o1, 0, 0, 0);

      ba = nba; bb = nbb; mva = nmva; mvb = nmvb;
    }

    // full row sum for qrow = ln15: reduce across the 4 quads
    float l = (l00 + l01) + (l10 + l11);
    l += __shfl_xor(l, 16);
    l += __shfl_xor(l, 32);

    const int R = qbase + ln15;
    if (R < 343) {
      float inv = 1.0f / l;
      size_t obase = ((size_t)b * 343 + R) * 96 + h * 32;
      half4 w0, w1;
#pragma unroll
      for (int rr = 0; rr < 4; rr++) {
        w0[rr] = f2h(o0[rr] * inv);
        w1[rr] = f2h(o1[rr] * inv);
      }
      *reinterpret_cast<half4*>(a_ws + obase + quad * 4) = w0;
      *reinterpret_cast<half4*>(a_ws + obase + 16 + quad * 4) = w1;
    }
  }
}

// ---------------- K3: out = attn @ Wproj^T + bproj (fp32 out) ----------------
__global__ __launch_bounds__(1024, 1) void k_proj(
    const _Float16* __restrict__ a_ws, const float* __restrict__ Wproj,
    const float* __restrict__ bproj, float* __restrict__ out) {
  __shared__ alignas(16) _Float16 Wl[96 * 104];
  const int tid = threadIdx.x;
  for (int i = tid; i < 2304; i += 1024) {
    f32x4 w4 = reinterpret_cast<const f32x4*>(Wproj)[i];
    int f = i * 4, row = f / 96, col = f - row * 96;
    _Float16* dst = &Wl[row * 104 + col];
    dst[0] = f2h(w4[0]); dst[1] = f2h(w4[1]); dst[2] = f2h(w4[2]); dst[3] = f2h(w4[3]);
  }
  __syncthreads();
  const int lane = tid & 63, wv = tid >> 6;
  const int ln15 = lane & 15, quad = lane >> 4;
  const int rowbase = blockIdx.x * 256 + wv * 16;
  half8 afr[3];
#pragma unroll
  for (int kt = 0; kt < 3; kt++) {
    afr[kt] = *reinterpret_cast<const half8*>(a_ws + (size_t)(rowbase + ln15) * 96 + kt * 32 + quad * 8);
  }
#pragma unroll
  for (int nt = 0; nt < 6; nt++) {
    f32x4 c = {0.f, 0.f, 0.f, 0.f};
#pragma unroll
    for (int kt = 0; kt < 3; kt++) {
      half8 bfr = *reinterpret_cast<const half8*>(&Wl[(nt * 16 + ln15) * 104 + kt * 32 + quad * 8]);
      c = __builtin_amdgcn_mfma_f32_16x16x32_f16(afr[kt], bfr, c, 0, 0, 0);
    }
    float bb = bproj[nt * 16 + ln15];
#pragma unroll
    for (int rr = 0; rr < 4; rr++) {
      int R = rowbase + quad * 4 + rr;
      out[(size_t)R * 96 + nt * 16 + ln15] = c[rr] + bb;
    }
  }
}

// ---------------- launch ----------------
extern "C" void kernel_launch(void* const* d_in, const int* in_sizes, int n_in,
                              void* d_out, int out_size, void* d_ws, size_t ws_size,
                              hipStream_t stream) {
  const float* x     = (const float*)d_in[0];
  const float* mask  = (const float*)d_in[1];
  const float* Wqkv  = (const float*)d_in[2];
  const float* bqkv  = (const float*)d_in[3];
  const float* Wproj = (const float*)d_in[4];
  const float* bproj = (const float*)d_in[5];
  const float* ls    = (const float*)d_in[6];
  const float* btab  = (const float*)d_in[7];
  const int*   rpi   = (const int*)d_in[8];
  float* out = (float*)d_out;

  char* ws = (char*)d_ws;
  _Float16* q_ws = (_Float16*)(ws);
  _Float16* k_ws = (_Float16*)(ws + 33718272);
  _Float16* v_ws = (_Float16*)(ws + 67436544);
  _Float16* a_ws = (_Float16*)(ws + 101154816);
  float* bfrag = (float*)(ws + 134873088);                // 3*484*64*4 f32 = 1,486,848 B
  unsigned char* mbf = (unsigned char*)(ws + 136359936);  // 64*484*64 u8 = 1,982,464 B
  // end = 138,342,400 B (verified in rounds 2 and 7)

  hipLaunchKernelGGL(k_prep, dim3(MASK_BLOCKS + BIAS_BLOCKS), dim3(256), 0, stream,
                     mask, rpi, btab, mbf, bfrag);
  hipLaunchKernelGGL(k_qkv, dim3(686), dim3(1024), 0, stream, x, Wqkv, bqkv, ls, q_ws, k_ws, v_ws);
  hipLaunchKernelGGL(k_attn, dim3(1536), dim3(512), 0, stream, q_ws, k_ws, v_ws,
                     bfrag, mbf, a_ws);
  hipLaunchKernelGGL(k_proj, dim3(686), dim3(1024), 0, stream, a_ws, Wproj, bproj, out);
}